// Round 8
// baseline (108.043 us; speedup 1.0000x reference)
//
#include <hip/hip_runtime.h>

namespace {

constexpr int NS = 256;      // samples
constexpr int MP = 128;      // patches
constexpr int TSTEPS = 200;  // timesteps
constexpr int BLK = 256;     // 4 waves, 1 wave/SIMD; chain-minimized loop

typedef float f2 __attribute__((ext_vector_type(2)));

__device__ __forceinline__ float4 ldg4(const float* p) {
  return *reinterpret_cast<const float4*>(p);
}
__device__ __forceinline__ float clamp01(float v) {
  return fminf(fmaxf(v, 0.0f), 1.0f);
}
// LDS-visibility barrier that does NOT drain vmcnt (stores stay in flight).
__device__ __forceinline__ void step_barrier() {
  asm volatile("s_waitcnt lgkmcnt(0)" ::: "memory");
  __builtin_amdgcn_s_barrier();
  asm volatile("" ::: "memory");
}
// guaranteed packed f32 FMA
__device__ __forceinline__ f2 pk_fma(f2 a, f2 b, f2 c) {
  f2 d;
  asm("v_pk_fma_f32 %0, %1, %2, %3" : "=v"(d) : "v"(a), "v"(b), "v"(c));
  return d;
}
// x + dpp_perm(y): 0xB1 quad_perm xor1, 0x4E quad_perm xor2, 0x124/0x128 ror4/8
template <int CTRL>
__device__ __forceinline__ float dpp_add(float x, float y) {
  int yi = __builtin_amdgcn_update_dpp(0, __float_as_int(y), CTRL, 0xF, 0xF, true);
  return x + __int_as_float(yi);
}
__device__ __forceinline__ float fold_x1(float x, float y, bool sel) {
  const float t = sel ? y : x;
  const float o = sel ? x : y;
  return dpp_add<0xB1>(t, o);
}
__device__ __forceinline__ float fold_x2(float x, float y, bool sel) {
  const float t = sel ? y : x;
  const float o = sel ? x : y;
  return dpp_add<0x4E>(t, o);
}
// Swizzled float4 index into Q staging.
__device__ __forceinline__ int qidx(int row, int c4) {
  return (row << 5) + (c4 ^ ((row >> 3) & 7));
}
// Gray-coded float slot for x row j (spreads the 16 read addrs across banks)
__device__ __forceinline__ int gslot(int j) {
  const int b = j >> 2;
  return ((b ^ (b >> 1)) << 2) | (j & 3);
}

__global__ __launch_bounds__(BLK, 1)
void sir_meta_kernel(const float* __restrict__ Rg,
                     const float* __restrict__ Tg,
                     const float* __restrict__ rho0g,
                     const float* __restrict__ betag,
                     float* __restrict__ outg)
{
  __shared__ __align__(16) float rs[MP];        // 1/rowsum
  __shared__ __align__(16) float sbin[MP];      // sqrt(beta/neff)
  __shared__ __align__(16) float scr[BLK];
  __shared__ __align__(16) float xb[2][MP];     // x, Gray-coded float4 blocks
  __shared__ __align__(16) float qlds[MP * MP]; // Q = R*diag(sbin), swizzled

  const int tid = threadIdx.x;
  const int n = blockIdx.x;
  const float* __restrict__ Rn = Rg + (size_t)n * MP * MP;

  // ---- S1: row sums -> rs = 1/rowsum ----
  {
    const int wave = tid >> 6;
    const int lane = tid & 63;
    const int half = lane >> 5;
    const int l32 = lane & 31;
    for (int it = 0; it < 16; ++it) {
      const int row = wave * 32 + it * 2 + half;
      float4 v = ldg4(Rn + row * MP + l32 * 4);
      float s = (v.x + v.y) + (v.z + v.w);
      s += __shfl_xor(s, 1);
      s += __shfl_xor(s, 2);
      s += __shfl_xor(s, 4);
      s += __shfl_xor(s, 8);
      s += __shfl_xor(s, 16);
      if (l32 == 0) rs[row] = 1.0f / s;
    }
  }
  __syncthreads();

  // ---- S2: neff[c] = sum_i Rraw[i][c]*rs[i] -> sbin = sqrt(beta/neff) ----
  {
    const int c = tid & 127;
    const int h = tid >> 7;
    float a = 0.0f;
    #pragma unroll 8
    for (int i = 0; i < 64; ++i) {
      const int ig = h * 64 + i;
      a = fmaf(Rn[ig * MP + c], rs[ig], a);
    }
    scr[tid] = a;
  }
  __syncthreads();
  if (tid < 128) sbin[tid] = sqrtf(betag[n] / (scr[tid] + scr[tid + 128]));
  __syncthreads();

  // ---- S3a: stage Q = Rraw * diag(sbin) into LDS, swizzled ----
  {
    float4* q4 = reinterpret_cast<float4*>(qlds);
    #pragma unroll
    for (int u = 0; u < 16; ++u) {
      const int fi = u * BLK + tid;
      const int r = fi >> 5, c4 = fi & 31;
      float4 rv = ldg4(Rn + fi * 4);
      float4 sv = *reinterpret_cast<const float4*>(&sbin[c4 * 4]);
      q4[qidx(r, c4)] =
          make_float4(rv.x * sv.x, rv.y * sv.y, rv.z * sv.z, rv.w * sv.w);
    }
  }
  __syncthreads();

  // Tile mapping: wave wv(0..3), group g(0..3) of 16 lanes, lane k(0..15).
  // Lane owns G rows [rbase..rbase+8) x cols [8k..8k+8). Group covers the
  // FULL 128-col span of its 8 rows -> reduce stays inside 16 lanes.
  const int wv = tid >> 6;
  const int g = (tid >> 4) & 3;
  const int k = tid & 15;
  const int rbase = wv * 32 + g * 8;
  const int cbase = k * 8;

  // ---- S3b: register-tiled GEMM; acc NEVER leaves registers ----
  float acc[64];
  #pragma unroll
  for (int i = 0; i < 64; ++i) acc[i] = 0.0f;
  {
    const float4* q4 = reinterpret_cast<const float4*>(qlds);
    for (int kk = 0; kk < 32; ++kk) {
      float4 qa[8], qb[8];
      #pragma unroll
      for (int r = 0; r < 8; ++r) qa[r] = q4[qidx(rbase + r, kk)];
      #pragma unroll
      for (int c = 0; c < 8; ++c) qb[c] = q4[qidx(cbase + c, kk)];
      #pragma unroll
      for (int r = 0; r < 8; ++r) {
        #pragma unroll
        for (int c = 0; c < 8; ++c) {
          float a = acc[r * 8 + c];
          a = fmaf(qa[r].x, qb[c].x, a);
          a = fmaf(qa[r].y, qb[c].y, a);
          a = fmaf(qa[r].z, qb[c].z, a);
          a = fmaf(qa[r].w, qb[c].w, a);
          acc[r * 8 + c] = a;
        }
      }
    }
  }
  // scale G = diag(rs) Q Q^T diag(rs), pack to f2 pairs for pk_fma
  f2 ac2[8][4];
  {
    float rsc[8];
    #pragma unroll
    for (int c = 0; c < 8; ++c) rsc[c] = rs[cbase + c];
    #pragma unroll
    for (int r = 0; r < 8; ++r) {
      const float rr = rs[rbase + r];
      #pragma unroll
      for (int q = 0; q < 4; ++q)
        ac2[r][q] = f2{acc[r * 8 + 2 * q] * rr * rsc[2 * q],
                       acc[r * 8 + 2 * q + 1] * rr * rsc[2 * q + 1]};
    }
  }

  // ---- S4: state init. Lane carries TWO rows: ja = rbase+(k&3), jb = ja+4 ----
  const int ja = rbase + (k & 3);
  const int jbr = ja + 4;
  const bool writer = (k < 4);
  const int wslA = gslot(ja);
  const int wslB = gslot(jbr);
  const int bA = (2 * k) ^ k;       // gray-spread x float4 blocks to read
  const int bB = (2 * k + 1) ^ k;

  const float* Tn = Tg + n * 9;
  const float T00 = Tn[0], T01 = Tn[1], T02 = Tn[2];
  const float T10 = Tn[3], T11 = Tn[4], T12 = Tn[5];
  const float T20 = Tn[6], T21 = Tn[7], T22 = Tn[8];

  const float* rpA = rho0g + ((size_t)n * MP + ja) * 3;
  const float* rpB = rho0g + ((size_t)n * MP + jbr) * 3;
  float a0 = rpA[0], a1 = rpA[1], a2 = rpA[2];
  float b0 = rpB[0], b1 = rpB[1], b2 = rpB[2];
  if (writer) {
    xb[0][wslA] = a0;
    xb[0][wslB] = b0;
  }
  __syncthreads();

  float4* outA = reinterpret_cast<float4*>(outg) + (size_t)n * TSTEPS * MP + ja;
  float4* outB = outA + 4;   // jbr = ja + 4

  const bool sa = (k & 1) != 0;
  const bool sb = (k & 2) != 0;

  for (int s = 0; s < TSTEPS; ++s) {
    // chain head: issue x reads IMMEDIATELY after barrier release
    const float4* xc4 = reinterpret_cast<const float4*>(xb[s & 1]);
    const float4 xA = xc4[bA];
    const float4 xB = xc4[bB];

    // off-chain: emit pre-update state (fire-and-forget)
    const float SA = 1.0f - ((a0 + a1) + a2);
    const float SB = 1.0f - ((b0 + b1) + b2);
    if (writer) {
      *outA = make_float4(SA, a0, a1, a2);
      *outB = make_float4(SB, b0, b1, b2);
    }
    outA += MP;
    outB += MP;

    // packed 8x8 tile matvec
    const f2 x0p = f2{xA.x, xA.y}, x1p = f2{xA.z, xA.w};
    const f2 x2p = f2{xB.x, xB.y}, x3p = f2{xB.z, xB.w};
    float p[8];
    #pragma unroll
    for (int r = 0; r < 8; ++r) {
      f2 sv = ac2[r][0] * x0p;
      sv = pk_fma(ac2[r][1], x1p, sv);
      sv = pk_fma(ac2[r][2], x2p, sv);
      sv = pk_fma(ac2[r][3], x3p, sv);
      p[r] = sv.x + sv.y;
    }

    // folded 16-lane reduce: xor1, xor2 fold 8 rows -> 2; ror4, ror8 finish.
    // Lane k ends with u0 = y[rbase+(k&3)], u1 = y[rbase+4+(k&3)].
    float q0 = fold_x1(p[0], p[1], sa);
    float q1 = fold_x1(p[2], p[3], sa);
    float q2 = fold_x1(p[4], p[5], sa);
    float q3 = fold_x1(p[6], p[7], sa);
    float u0 = fold_x2(q0, q1, sb);
    float u1 = fold_x2(q2, q3, sb);
    u0 = dpp_add<0x124>(u0, u0);
    u0 = dpp_add<0x128>(u0, u0);
    u1 = dpp_add<0x124>(u1, u1);
    u1 = dpp_add<0x128>(u1, u1);

    // chain tail: n0 for both rows -> x write
    const float niA = SA * u0;
    const float niB = SB * u1;
    const float na0 = clamp01(fmaf(a0, T00, fmaf(a1, T10, fmaf(a2, T20, niA))));
    const float nb0 = clamp01(fmaf(b0, T00, fmaf(b1, T10, fmaf(b2, T20, niB))));
    if (writer) {
      float* xn = xb[(s & 1) ^ 1];
      xn[wslA] = na0;
      xn[wslB] = nb0;
    }
    // off-chain (drains while write completes)
    const float na1 = clamp01(fmaf(a0, T01, fmaf(a1, T11, a2 * T21)));
    const float na2 = clamp01(fmaf(a0, T02, fmaf(a1, T12, a2 * T22)));
    const float nb1 = clamp01(fmaf(b0, T01, fmaf(b1, T11, b2 * T21)));
    const float nb2 = clamp01(fmaf(b0, T02, fmaf(b1, T12, b2 * T22)));
    a0 = na0; a1 = na1; a2 = na2;
    b0 = nb0; b1 = nb1; b2 = nb2;

    step_barrier();
  }
}

} // namespace

extern "C" void kernel_launch(void* const* d_in, const int* in_sizes, int n_in,
                              void* d_out, int out_size, void* d_ws, size_t ws_size,
                              hipStream_t stream)
{
  const float* Rg    = (const float*)d_in[0];
  const float* Tg    = (const float*)d_in[1];
  const float* rho0g = (const float*)d_in[2];
  const float* betag = (const float*)d_in[3];
  float* outg = (float*)d_out;
  sir_meta_kernel<<<NS, BLK, 0, stream>>>(Rg, Tg, rho0g, betag, outg);
}

// Round 9
// 97.703 us; speedup vs baseline: 1.1058x; 1.1058x over previous
//
#include <hip/hip_runtime.h>

namespace {

constexpr int NS = 256;      // samples
constexpr int MP = 128;      // patches
constexpr int TSTEPS = 200;  // timesteps
constexpr int BLK = 512;     // 8 waves -> 2 waves/SIMD

typedef float f2 __attribute__((ext_vector_type(2)));

__device__ __forceinline__ float4 ldg4(const float* p) {
  return *reinterpret_cast<const float4*>(p);
}
__device__ __forceinline__ float clamp01(float v) {
  return fminf(fmaxf(v, 0.0f), 1.0f);
}
// LDS-visibility barrier that does NOT drain vmcnt (stores stay in flight).
__device__ __forceinline__ void step_barrier() {
  asm volatile("s_waitcnt lgkmcnt(0)" ::: "memory");
  __builtin_amdgcn_s_barrier();
  asm volatile("" ::: "memory");
}
// guaranteed packed f32 FMA
__device__ __forceinline__ f2 pk_fma(f2 a, f2 b, f2 c) {
  f2 d;
  asm("v_pk_fma_f32 %0, %1, %2, %3" : "=v"(d) : "v"(a), "v"(b), "v"(c));
  return d;
}
// x + dpp_perm(y): 0xB1 quad_perm xor1, 0x4E quad_perm xor2, 0x124/0x128 ror4/8
template <int CTRL>
__device__ __forceinline__ float dpp_add(float x, float y) {
  int yi = __builtin_amdgcn_update_dpp(0, __float_as_int(y), CTRL, 0xF, 0xF, true);
  return x + __int_as_float(yi);
}
// Row-preserving fold over xor1: lane-swapped operands so even lanes keep
// x's row, odd lanes keep y's row, each summed over the lane pair's columns.
__device__ __forceinline__ float fold_x1(float x, float y, bool sel) {
  const float t = sel ? y : x;
  const float o = sel ? x : y;
  return dpp_add<0xB1>(t, o);
}
// Swizzled float4 index into Q staging.
__device__ __forceinline__ int qidx(int row, int c4) {
  return (row << 5) + (c4 ^ ((row >> 3) & 7));
}
// Gray-coded float slot for x row j (block position gray-coded, content order
// inside each float4 block preserved).
__device__ __forceinline__ int gslot(int j) {
  const int b = j >> 2;
  return ((b ^ (b >> 1)) << 2) | (j & 3);
}

__global__ __launch_bounds__(BLK, 2)
void sir_meta_kernel(const float* __restrict__ Rg,
                     const float* __restrict__ Tg,
                     const float* __restrict__ rho0g,
                     const float* __restrict__ betag,
                     float* __restrict__ outg)
{
  __shared__ __align__(16) float rs[MP];         // 1/rowsum
  __shared__ __align__(16) float sbin[MP];       // sqrt(beta/neff)
  __shared__ __align__(16) float scr[BLK];
  __shared__ __align__(16) float xb[2][MP];      // x, Gray-coded blocks
  __shared__ __align__(16) float qlds[MP * MP];  // Q = R*diag(sbin), swizzled
  __shared__ __align__(16) float glds[MP * 132]; // G, stride 132 floats

  const int tid = threadIdx.x;
  const int n = blockIdx.x;
  const float* __restrict__ Rn = Rg + (size_t)n * MP * MP;

  // ---- S1: row sums -> rs = 1/rowsum ----
  {
    const int wave = tid >> 6;
    const int lane = tid & 63;
    const int half = lane >> 5;
    const int l32 = lane & 31;
    for (int it = 0; it < 8; ++it) {
      const int row = wave * 16 + it * 2 + half;
      float4 v = ldg4(Rn + row * MP + l32 * 4);
      float s = (v.x + v.y) + (v.z + v.w);
      s += __shfl_xor(s, 1);
      s += __shfl_xor(s, 2);
      s += __shfl_xor(s, 4);
      s += __shfl_xor(s, 8);
      s += __shfl_xor(s, 16);
      if (l32 == 0) rs[row] = 1.0f / s;
    }
  }
  __syncthreads();

  // ---- S2: neff[c] = sum_i Rraw[i][c]*rs[i] -> sbin = sqrt(beta/neff) ----
  {
    const int c = tid & 127;
    const int h = tid >> 7;
    float a = 0.0f;
    #pragma unroll 8
    for (int i = 0; i < 32; ++i) {
      const int ig = h * 32 + i;
      a = fmaf(Rn[ig * MP + c], rs[ig], a);
    }
    scr[tid] = a;
  }
  __syncthreads();
  if (tid < 128)
    sbin[tid] = sqrtf(betag[n] /
        (((scr[tid] + scr[tid + 128]) + (scr[tid + 256] + scr[tid + 384]))));
  __syncthreads();

  // ---- S3a: stage Q = Rraw * diag(sbin) into LDS, swizzled ----
  {
    float4* q4 = reinterpret_cast<float4*>(qlds);
    #pragma unroll
    for (int u = 0; u < 8; ++u) {
      const int fi = u * BLK + tid;
      const int r = fi >> 5, c4 = fi & 31;
      float4 rv = ldg4(Rn + fi * 4);
      float4 sv = *reinterpret_cast<const float4*>(&sbin[c4 * 4]);
      q4[qidx(r, c4)] =
          make_float4(rv.x * sv.x, rv.y * sv.y, rv.z * sv.z, rv.w * sv.w);
    }
  }
  __syncthreads();

  // ---- S3b: 4-wave 8x8-tile GEMM  G = diag(rs) * Q Q^T * diag(rs) ----
  if (tid < 256) {
    const int wv4 = tid >> 6;
    const int g4i = (tid >> 4) & 3;
    const int k4 = tid & 15;
    const int rb = wv4 * 32 + g4i * 8;
    const int cb = k4 * 8;
    float acc[64];
    #pragma unroll
    for (int i = 0; i < 64; ++i) acc[i] = 0.0f;
    {
      const float4* q4 = reinterpret_cast<const float4*>(qlds);
      for (int kk = 0; kk < 32; ++kk) {
        float4 qa[8], qb[8];
        #pragma unroll
        for (int r = 0; r < 8; ++r) qa[r] = q4[qidx(rb + r, kk)];
        #pragma unroll
        for (int c = 0; c < 8; ++c) qb[c] = q4[qidx(cb + c, kk)];
        #pragma unroll
        for (int r = 0; r < 8; ++r) {
          #pragma unroll
          for (int c = 0; c < 8; ++c) {
            float a = acc[r * 8 + c];
            a = fmaf(qa[r].x, qb[c].x, a);
            a = fmaf(qa[r].y, qb[c].y, a);
            a = fmaf(qa[r].z, qb[c].z, a);
            a = fmaf(qa[r].w, qb[c].w, a);
            acc[r * 8 + c] = a;
          }
        }
      }
    }
    {
      float rsc[8];
      #pragma unroll
      for (int c = 0; c < 8; ++c) rsc[c] = rs[cb + c];
      float4* g4p = reinterpret_cast<float4*>(glds);
      #pragma unroll
      for (int r = 0; r < 8; ++r) {
        const float rr = rs[rb + r];
        float4 lo = make_float4(acc[r*8+0] * rr * rsc[0], acc[r*8+1] * rr * rsc[1],
                                acc[r*8+2] * rr * rsc[2], acc[r*8+3] * rr * rsc[3]);
        float4 hi = make_float4(acc[r*8+4] * rr * rsc[4], acc[r*8+5] * rr * rsc[5],
                                acc[r*8+6] * rr * rsc[6], acc[r*8+7] * rr * rsc[7]);
        g4p[(rb + r) * 33 + 2 * k4]     = lo;
        g4p[(rb + r) * 33 + 2 * k4 + 1] = hi;
      }
    }
  }
  __syncthreads();

  // ---- redistribute: 8-wave loop tiling. Lane owns 4 rows x 8 cols. ----
  const int wv = tid >> 6;
  const int g = (tid >> 4) & 3;
  const int k = tid & 15;
  const int rbase = wv * 16 + g * 4;

  f2 ac2[4][4];
  {
    const float4* g4p = reinterpret_cast<const float4*>(glds);
    #pragma unroll
    for (int r = 0; r < 4; ++r) {
      float4 lo = g4p[(rbase + r) * 33 + 2 * k];
      float4 hi = g4p[(rbase + r) * 33 + 2 * k + 1];
      ac2[r][0] = f2{lo.x, lo.y}; ac2[r][1] = f2{lo.z, lo.w};
      ac2[r][2] = f2{hi.x, hi.y}; ac2[r][3] = f2{hi.z, hi.w};
    }
  }

  // ---- S4: lane carries ADJACENT rows ja = rbase+2*(k&1), jb = ja+1 ----
  const int ja = rbase + 2 * (k & 1);
  const bool writer = (k < 2);
  const int wslA = gslot(ja);        // even slot; jb is wslA+1 (same block)
  const int bA = (2 * k) ^ k;        // gray-spread x float4 blocks to read
  const int bB = (2 * k + 1) ^ k;

  const float* Tn = Tg + n * 9;
  const float T00 = Tn[0], T01 = Tn[1], T02 = Tn[2];
  const float T10 = Tn[3], T11 = Tn[4], T12 = Tn[5];
  const float T20 = Tn[6], T21 = Tn[7], T22 = Tn[8];

  const float* rpA = rho0g + ((size_t)n * MP + ja) * 3;
  float a0 = rpA[0], a1 = rpA[1], a2 = rpA[2];
  float b0 = rpA[3], b1 = rpA[4], b2 = rpA[5];   // row ja+1
  if (writer) *reinterpret_cast<f2*>(&xb[0][wslA]) = f2{a0, b0};
  __syncthreads();

  float4* outA = reinterpret_cast<float4*>(outg) + (size_t)n * TSTEPS * MP + ja;
  float4* outB = outA + 1;   // row ja+1

  const bool sa = (k & 1) != 0;

  for (int s = 0; s < TSTEPS; ++s) {
    // chain head: x reads issue immediately at barrier release
    const float4* xc4 = reinterpret_cast<const float4*>(xb[s & 1]);
    const float4 xA = xc4[bA];
    const float4 xB = xc4[bB];

    // off-chain while reads are in flight
    const float SA = 1.0f - ((a0 + a1) + a2);
    const float SB = 1.0f - ((b0 + b1) + b2);

    // packed 4x8 tile matvec
    const f2 x0p = f2{xA.x, xA.y}, x1p = f2{xA.z, xA.w};
    const f2 x2p = f2{xB.x, xB.y}, x3p = f2{xB.z, xB.w};
    float p[4];
    #pragma unroll
    for (int r = 0; r < 4; ++r) {
      f2 sv = ac2[r][0] * x0p;
      sv = pk_fma(ac2[r][1], x1p, sv);
      sv = pk_fma(ac2[r][2], x2p, sv);
      sv = pk_fma(ac2[r][3], x3p, sv);
      p[r] = sv.x + sv.y;
    }

    // folded reduce -> lane holds ADJACENT rows: u0=row ja (2*(k&1)),
    // u1=row ja+1. xor1 folds {p0,p2}/{p1,p3}; xor2+ror4+ror8 pure adds.
    float u0 = fold_x1(p[0], p[2], sa);
    float u1 = fold_x1(p[1], p[3], sa);
    u0 = dpp_add<0x4E>(u0, u0);
    u1 = dpp_add<0x4E>(u1, u1);
    u0 = dpp_add<0x124>(u0, u0);
    u1 = dpp_add<0x124>(u1, u1);
    u0 = dpp_add<0x128>(u0, u0);
    u1 = dpp_add<0x128>(u1, u1);

    // chain tail: n0 for both rows -> single b64 x-write
    const float na0 = clamp01(fmaf(a0, T00, fmaf(a1, T10, fmaf(a2, T20, SA * u0))));
    const float nb0 = clamp01(fmaf(b0, T00, fmaf(b1, T10, fmaf(b2, T20, SB * u1))));
    if (writer)
      *reinterpret_cast<f2*>(&xb[(s & 1) ^ 1][wslA]) = f2{na0, nb0};

    // write-ack shadow: out stores (VMEM, not counted by lgkmcnt)
    if (writer) {
      *outA = make_float4(SA, a0, a1, a2);
      *outB = make_float4(SB, b0, b1, b2);
    }
    outA += MP;
    outB += MP;
    const float o0A = a0, o1A = a1, o2A = a2;
    const float o0B = b0, o1B = b1, o2B = b2;
    a0 = na0;
    b0 = nb0;

    step_barrier();

    // post-barrier shadow (hidden under next step's x-read latency)
    a1 = clamp01(fmaf(o0A, T01, fmaf(o1A, T11, o2A * T21)));
    a2 = clamp01(fmaf(o0A, T02, fmaf(o1A, T12, o2A * T22)));
    b1 = clamp01(fmaf(o0B, T01, fmaf(o1B, T11, o2B * T21)));
    b2 = clamp01(fmaf(o0B, T02, fmaf(o1B, T12, o2B * T22)));
  }
}

} // namespace

extern "C" void kernel_launch(void* const* d_in, const int* in_sizes, int n_in,
                              void* d_out, int out_size, void* d_ws, size_t ws_size,
                              hipStream_t stream)
{
  const float* Rg    = (const float*)d_in[0];
  const float* Tg    = (const float*)d_in[1];
  const float* rho0g = (const float*)d_in[2];
  const float* betag = (const float*)d_in[3];
  float* outg = (float*)d_out;
  sir_meta_kernel<<<NS, BLK, 0, stream>>>(Rg, Tg, rho0g, betag, outg);
}